// Round 14
// baseline (5313.001 us; speedup 1.0000x reference)
//
#include <hip/hip_runtime.h>
#include <hip/hip_bf16.h>
#include <math.h>

#define NN 10000
#define NE 100000
#define SPGc 1250
#define NG 8
#define NL 5
#define ECHK 50000

__device__ __forceinline__ int imin(int a, int b) { return a < b ? a : b; }

// ---------------- node types ----------------
__global__ __launch_bounds__(256) void k_types(const float* __restrict__ x, int* __restrict__ types) {
    int i = blockIdx.x * 256 + threadIdx.x;
    if (i < NN) {
        float v = rintf(x[(size_t)i * 16 + 2] * 3.0f);
        v = fminf(fmaxf(v, 1.0f), 3.0f);
        types[i] = (int)v - 1;
    }
}

// ---------------- CSR build ----------------
__global__ __launch_bounds__(256) void k_hist(const int* __restrict__ dst, int* __restrict__ deg) {
    int e = blockIdx.x * 256 + threadIdx.x;
    if (e < NE) atomicAdd(&deg[dst[e]], 1);
}

__global__ __launch_bounds__(256) void k_scan(const int* __restrict__ deg, int* __restrict__ row_ptr,
                                              int* __restrict__ cursor) {
    __shared__ int buf[256];
    int tid = threadIdx.x;
    int base = 0;
    for (int c = 0; c < NN; c += 256) {
        int i = c + tid;
        int v = (i < NN) ? deg[i] : 0;
        buf[tid] = v;
        __syncthreads();
        for (int off = 1; off < 256; off <<= 1) {
            int t = (tid >= off) ? buf[tid - off] : 0;
            __syncthreads();
            buf[tid] += t;
            __syncthreads();
        }
        if (i < NN) {
            row_ptr[i + 1] = base + buf[tid];
            cursor[i] = base + buf[tid] - v;
        }
        __syncthreads();
        base += buf[255];
        __syncthreads();
    }
    if (tid == 0) row_ptr[0] = 0;
}

__global__ __launch_bounds__(256) void k_scatter(const int* __restrict__ dst, int* __restrict__ cursor,
                                                 int* __restrict__ csr) {
    int e = blockIdx.x * 256 + threadIdx.x;
    if (e < NE) {
        int p = atomicAdd(&cursor[dst[e]], 1);
        csr[p] = e;
    }
}

// ---------------- per-type node encoder (fp32) ----------------
__global__ __launch_bounds__(256) void k_enc(const float* __restrict__ x, const float* __restrict__ pe,
        const int* __restrict__ types,
        const float* __restrict__ w1, const float* __restrict__ b1,
        const float* __restrict__ w2, const float* __restrict__ b2,
        float* __restrict__ h_nodes) {
    int n = blockIdx.x;
    int j = threadIdx.x;
    __shared__ float inp[21];
    __shared__ float hid[256];
    if (j < 16) inp[j] = x[(size_t)n * 16 + j];
    else if (j < 21) inp[j] = pe[(size_t)n * 5 + (j - 16)];
    __syncthreads();
    int t = types[n];
    const float* W1 = w1 + (size_t)t * 21 * 256;
    float a = b1[t * 256 + j];
    #pragma unroll
    for (int i = 0; i < 21; ++i) a = fmaf(inp[i], W1[i * 256 + j], a);
    hid[j] = fmaxf(a, 0.f);
    __syncthreads();
    const float* W2 = w2 + (size_t)t * 256 * 256;
    float o = b2[t * 256 + j];
    #pragma unroll 8
    for (int k = 0; k < 256; ++k) o = fmaf(hid[k], W2[k * 256 + j], o);
    h_nodes[(size_t)n * 256 + j] = o;
}

// ---------------- small fp32 GEMM (edge encoder layer 1, K=8), relu out ----------------
__global__ __launch_bounds__(256) void gemm64(int Mrows, int K, int Nout,
        const float* __restrict__ A0, int lda,
        const float* __restrict__ W, const float* __restrict__ bias,
        float* __restrict__ C) {
    __shared__ __align__(16) float As[16][68];
    __shared__ __align__(16) float Ws[16][64];
    int tid = threadIdx.x;
    int tx = tid & 15, ty = tid >> 4;
    int blockRow = blockIdx.x * 64;
    int ncol0 = blockIdx.y * 64;
    float acc[4][4];
    #pragma unroll
    for (int i = 0; i < 4; ++i)
        #pragma unroll
        for (int j = 0; j < 4; ++j) acc[i][j] = 0.f;

    for (int k0 = 0; k0 < K; k0 += 16) {
        #pragma unroll
        for (int i = 0; i < 4; ++i) {
            int id = tid + 256 * i;
            int kk = id & 15, r = id >> 4;
            int grow = blockRow + r;
            int k = k0 + kk;
            float v = 0.f;
            if (grow < Mrows && k < K) v = A0[(size_t)grow * lda + k];
            As[kk][r] = v;
        }
        #pragma unroll
        for (int i = 0; i < 4; ++i) {
            int id = tid + 256 * i;
            int c = id & 63, kk = id >> 6;
            int k = k0 + kk;
            Ws[kk][c] = (k < K) ? W[(size_t)k * Nout + ncol0 + c] : 0.f;
        }
        __syncthreads();
        #pragma unroll
        for (int kk = 0; kk < 16; ++kk) {
            const float4 a4 = *(const float4*)&As[kk][ty << 2];
            const float4 w4 = *(const float4*)&Ws[kk][tx << 2];
            float av[4] = {a4.x, a4.y, a4.z, a4.w};
            float wv[4] = {w4.x, w4.y, w4.z, w4.w};
            #pragma unroll
            for (int i = 0; i < 4; ++i)
                #pragma unroll
                for (int j = 0; j < 4; ++j)
                    acc[i][j] = fmaf(av[i], wv[j], acc[i][j]);
        }
        __syncthreads();
    }
    #pragma unroll
    for (int i = 0; i < 4; ++i) {
        int grow = blockRow + (ty << 2) + i;
        if (grow >= Mrows) continue;
        size_t base = (size_t)grow * Nout + ncol0 + (tx << 2);
        #pragma unroll
        for (int j = 0; j < 4; ++j)
            C[base + j] = fmaxf(acc[i][j] + bias[ncol0 + (tx << 2) + j], 0.f);
    }
}

// ---------------- big edge GEMM: 128x128 tile (Nout=256, y half), K=256, 8x8/thread ----------------
// Software-pipelined staging: prefetch next k-tile into regs during compute.
template<bool GATHER, bool RELU, bool RES>
__global__ __launch_bounds__(256) void gemm_big(int Mrows,
        const float* __restrict__ A,
        const float* __restrict__ W, const float* __restrict__ bias,
        const int* __restrict__ gs, const int* __restrict__ gd, int gOfs,
        const float* __restrict__ Pa, const float* __restrict__ Pb,
        const float* __restrict__ Res, float* __restrict__ C) {
    __shared__ __align__(16) float As[16][132];      // 8448 B, [k][row]
    __shared__ __align__(16) float Ws[16][16][10];   // 6400 B, [k][colgroup][8 used]
    int tid = threadIdx.x;
    int blockRow = blockIdx.x * 128;
    int ncol0 = blockIdx.y * 128;
    int rg = tid >> 4, cg = tid & 15;                // rows rg*8..+7, cols cg*8..+7
    int srow = tid >> 1, skh = (tid & 1) * 8;        // A staging
    int swk = tid >> 4, scg = tid & 15;              // W staging
    float acc[8][8];
    #pragma unroll
    for (int i = 0; i < 8; ++i)
        #pragma unroll
        for (int n = 0; n < 8; ++n) acc[i][n] = 0.f;

    int arow = imin(blockRow + srow, Mrows - 1);
    const float* aP = A + (size_t)arow * 256 + skh;
    const float* wP = W + (size_t)swk * 256 + ncol0 + scg * 8;

    float4 pa0 = *(const float4*)(aP);
    float4 pa1 = *(const float4*)(aP + 4);
    float4 pw0 = *(const float4*)(wP);
    float4 pw1 = *(const float4*)(wP + 4);

    for (int k0 = 0; k0 < 256; k0 += 16) {
        As[skh + 0][srow] = pa0.x; As[skh + 1][srow] = pa0.y;
        As[skh + 2][srow] = pa0.z; As[skh + 3][srow] = pa0.w;
        As[skh + 4][srow] = pa1.x; As[skh + 5][srow] = pa1.y;
        As[skh + 6][srow] = pa1.z; As[skh + 7][srow] = pa1.w;
        *(float4*)&Ws[swk][scg][0] = pw0;
        *(float4*)&Ws[swk][scg][4] = pw1;
        __syncthreads();
        if (k0 + 16 < 256) {
            pa0 = *(const float4*)(aP + k0 + 16);
            pa1 = *(const float4*)(aP + k0 + 20);
            const float* wn = wP + (size_t)(k0 + 16) * 256;
            pw0 = *(const float4*)(wn);
            pw1 = *(const float4*)(wn + 4);
        }
        #pragma unroll
        for (int kk = 0; kk < 16; ++kk) {
            const float4 a0 = *(const float4*)&As[kk][rg << 3];
            const float4 a1 = *(const float4*)&As[kk][(rg << 3) + 4];
            float av[8] = {a0.x, a0.y, a0.z, a0.w, a1.x, a1.y, a1.z, a1.w};
            const float4 w0 = *(const float4*)&Ws[kk][cg][0];
            const float4 w1 = *(const float4*)&Ws[kk][cg][4];
            float wv[8] = {w0.x, w0.y, w0.z, w0.w, w1.x, w1.y, w1.z, w1.w};
            #pragma unroll
            for (int i = 0; i < 8; ++i)
                #pragma unroll
                for (int j = 0; j < 8; ++j)
                    acc[i][j] = fmaf(av[i], wv[j], acc[i][j]);
        }
        __syncthreads();
    }
    // ---- epilogue ----
    int colb = ncol0 + (cg << 3);
    #pragma unroll
    for (int i = 0; i < 8; ++i) {
        int row = blockRow + (rg << 3) + i;
        if (row >= Mrows) continue;
        size_t base = (size_t)row * 256 + colb;
        const float* par = nullptr;
        const float* pbr = nullptr;
        if (GATHER) {
            par = Pa + (size_t)gs[gOfs + row] * 256 + colb;
            pbr = Pb + (size_t)gd[gOfs + row] * 256 + colb;
        }
        #pragma unroll
        for (int q = 0; q < 2; ++q) {
            const float4 b4 = *(const float4*)(bias + colb + q * 4);
            float v[4] = {acc[i][q * 4 + 0] + b4.x, acc[i][q * 4 + 1] + b4.y,
                          acc[i][q * 4 + 2] + b4.z, acc[i][q * 4 + 3] + b4.w};
            if (GATHER) {
                const float4 pa4 = *(const float4*)(par + q * 4);
                const float4 pb4 = *(const float4*)(pbr + q * 4);
                v[0] += pa4.x + pb4.x; v[1] += pa4.y + pb4.y;
                v[2] += pa4.z + pb4.z; v[3] += pa4.w + pb4.w;
            }
            if (RELU) {
                v[0] = fmaxf(v[0], 0.f); v[1] = fmaxf(v[1], 0.f);
                v[2] = fmaxf(v[2], 0.f); v[3] = fmaxf(v[3], 0.f);
            }
            if (RES) {
                const float4 rv = *(const float4*)(Res + base + q * 4);
                v[0] += rv.x; v[1] += rv.y; v[2] += rv.z; v[3] += rv.w;
            }
            float4 o; o.x = v[0]; o.y = v[1]; o.z = v[2]; o.w = v[3];
            *(float4*)(C + base + q * 4) = o;
        }
    }
}

// ---------------- node fp32 GEMM: BM=64, BN=128, BK=16, 4x8/thread; pipelined; grid.z batches W/C ----------------
template<int AMODE, bool RELU, bool HASRES, bool HASBIAS>
__global__ __launch_bounds__(256) void gemm_f32(int Mrows, int K, int Nout,
        const float* __restrict__ A0, const float* __restrict__ A1, int lda,
        const float* __restrict__ W, const float* __restrict__ bias,
        const float* __restrict__ ResF, float resScale,
        float* __restrict__ C, int zW, int zC) {
    __shared__ __align__(16) float As[16][68];
    __shared__ __align__(16) float Ws[16][16][10];
    int tid = threadIdx.x;
    int blockRow = blockIdx.x * 64;
    int ncol0 = blockIdx.y * 128;
    W += (size_t)blockIdx.z * zW;
    C += (size_t)blockIdx.z * zC;
    int rg = tid >> 4, cg = tid & 15;
    int sar = tid >> 2, sak = (tid & 3) * 4;
    int swk = tid >> 4, scg = tid & 15;
    float acc[4][8];
    #pragma unroll
    for (int i = 0; i < 4; ++i)
        #pragma unroll
        for (int n = 0; n < 8; ++n) acc[i][n] = 0.f;

    int arowA = imin(blockRow + sar, Mrows - 1);
    const float* wPb = W + (size_t)swk * Nout + ncol0 + scg * 8;

    float4 pa, pw0, pw1;
    {
        if (AMODE == 0) {
            pa = *(const float4*)(A0 + (size_t)arowA * lda + sak);
        } else {
            int k = sak;
            pa = (k < 256) ? *(const float4*)(A0 + (size_t)arowA * 256 + k)
                           : *(const float4*)(A1 + (size_t)arowA * 256 + (k - 256));
        }
        pw0 = *(const float4*)(wPb);
        pw1 = *(const float4*)(wPb + 4);
    }

    for (int k0 = 0; k0 < K; k0 += 16) {
        As[sak + 0][sar] = pa.x;
        As[sak + 1][sar] = pa.y;
        As[sak + 2][sar] = pa.z;
        As[sak + 3][sar] = pa.w;
        *(float4*)&Ws[swk][scg][0] = pw0;
        *(float4*)&Ws[swk][scg][4] = pw1;
        __syncthreads();
        if (k0 + 16 < K) {
            int kn = k0 + 16 + sak;
            if (AMODE == 0) {
                pa = *(const float4*)(A0 + (size_t)arowA * lda + kn);
            } else {
                pa = (kn < 256) ? *(const float4*)(A0 + (size_t)arowA * 256 + kn)
                                : *(const float4*)(A1 + (size_t)arowA * 256 + (kn - 256));
            }
            const float* wn = wPb + (size_t)(k0 + 16) * Nout;
            pw0 = *(const float4*)(wn);
            pw1 = *(const float4*)(wn + 4);
        }
        #pragma unroll
        for (int kk = 0; kk < 16; ++kk) {
            const float4 a4 = *(const float4*)&As[kk][rg << 2];
            float av[4] = {a4.x, a4.y, a4.z, a4.w};
            const float4 w0 = *(const float4*)&Ws[kk][cg][0];
            const float4 w1 = *(const float4*)&Ws[kk][cg][4];
            float wv[8] = {w0.x, w0.y, w0.z, w0.w, w1.x, w1.y, w1.z, w1.w};
            #pragma unroll
            for (int i = 0; i < 4; ++i)
                #pragma unroll
                for (int j = 0; j < 8; ++j)
                    acc[i][j] = fmaf(av[i], wv[j], acc[i][j]);
        }
        __syncthreads();
    }
    #pragma unroll
    for (int i = 0; i < 4; ++i) {
        int grow = blockRow + (rg << 2) + i;
        if (grow >= Mrows) continue;
        size_t crow = (size_t)grow;
        int colb = ncol0 + (cg << 3);
        #pragma unroll
        for (int q = 0; q < 2; ++q) {
            float v[4];
            #pragma unroll
            for (int j = 0; j < 4; ++j) v[j] = acc[i][q * 4 + j];
            if (HASBIAS) {
                const float4 b4 = *(const float4*)(bias + colb + q * 4);
                v[0] += b4.x; v[1] += b4.y; v[2] += b4.z; v[3] += b4.w;
            }
            if (RELU) {
                v[0] = fmaxf(v[0], 0.f); v[1] = fmaxf(v[1], 0.f);
                v[2] = fmaxf(v[2], 0.f); v[3] = fmaxf(v[3], 0.f);
            }
            if (HASRES) {
                const float4 rv = *(const float4*)(ResF + crow * Nout + colb + q * 4);
                v[0] += resScale * rv.x; v[1] += resScale * rv.y;
                v[2] += resScale * rv.z; v[3] += resScale * rv.w;
            }
            float4 o; o.x = v[0]; o.y = v[1]; o.z = v[2]; o.w = v[3];
            *(float4*)(C + crow * Nout + colb + q * 4) = o;
        }
    }
}

// ---------------- segment-sum ----------------
__global__ __launch_bounds__(256) void k_mnode(const float* __restrict__ h_edges,
        const int* __restrict__ row_ptr, const int* __restrict__ csr, float* __restrict__ m_node) {
    int n = blockIdx.x * 4 + (threadIdx.x >> 6);
    int lane = threadIdx.x & 63;
    if (n >= NN) return;
    float a0 = 0.f, a1 = 0.f, a2 = 0.f, a3 = 0.f;
    int s = row_ptr[n], e = row_ptr[n + 1];
    for (int i = s; i < e; ++i) {
        int ed = csr[i];
        const float4 v = *(const float4*)(h_edges + (size_t)ed * 256 + (lane << 2));
        a0 += v.x; a1 += v.y; a2 += v.z; a3 += v.w;
    }
    float4 r; r.x = a0; r.y = a1; r.z = a2; r.w = a3;
    *(float4*)(m_node + (size_t)n * 256 + (lane << 2)) = r;
}

// ---------------- flash attention: round-12 math + minimal double-buffered staging ----------------
__global__ __launch_bounds__(256) void k_attn(const float* __restrict__ qkv, float* __restrict__ obuf) {
    int gh = blockIdx.y;
    int g = gh >> 2, h = gh & 3;
    int q0 = blockIdx.x * 64;
    int tid = threadIdx.x;
    int r = tid >> 2, q4 = tid & 3;
    int d0 = q4 * 16;
    __shared__ __align__(16) float Ks[2][32][68];
    __shared__ __align__(16) float Vs[2][32][68];
    const float* base = qkv + (size_t)g * SPGc * 768;
    int my_s = q0 + r;
    bool rowok = my_s < SPGc;
    float qreg[16];
    #pragma unroll
    for (int dd = 0; dd < 16; ++dd) qreg[dd] = 0.f;
    if (rowok) {
        const float* qp = base + (size_t)my_s * 768 + h * 64 + d0;
        #pragma unroll
        for (int dd = 0; dd < 16; ++dd) qreg[dd] = qp[dd];
    }
    float m = -1e30f, l = 0.f;
    float oacc[16];
    #pragma unroll
    for (int dd = 0; dd < 16; ++dd) oacc[dd] = 0.f;

    int srow = tid >> 3, sc8 = (tid & 7) * 8;
    const int NIT = (SPGc + 31) / 32;   // 40
    float4 pk0, pk1, pv0, pv1;

    // preload tile 0 into buffer 0
    {
        const float* kp = base + (size_t)srow * 768 + h * 64 + sc8;
        pk0 = *(const float4*)(kp + 256);
        pk1 = *(const float4*)(kp + 260);
        pv0 = *(const float4*)(kp + 512);
        pv1 = *(const float4*)(kp + 516);
    }
    *(float4*)&Ks[0][srow][sc8]     = pk0;
    *(float4*)&Ks[0][srow][sc8 + 4] = pk1;
    *(float4*)&Vs[0][srow][sc8]     = pv0;
    *(float4*)&Vs[0][srow][sc8 + 4] = pv1;
    __syncthreads();

    for (int it = 0; it < NIT; ++it) {
        int t0 = it * 32;
        int cb = it & 1;
        // issue next-tile loads (in flight during compute of current tile)
        if (it + 1 < NIT) {
            int s = t0 + 32 + srow;
            if (s >= SPGc) s = SPGc - 1;      // clamp: garbage rows masked by score -1e30
            const float* kp = base + (size_t)s * 768 + h * 64 + sc8;
            pk0 = *(const float4*)(kp + 256);
            pk1 = *(const float4*)(kp + 260);
            pv0 = *(const float4*)(kp + 512);
            pv1 = *(const float4*)(kp + 516);
        }
        float sc[32];
        #pragma unroll
        for (int j = 0; j < 32; ++j) {
            float p = 0.f;
            #pragma unroll
            for (int dd = 0; dd < 16; dd += 4) {
                const float4 k4 = *(const float4*)&Ks[cb][j][d0 + dd];
                p = fmaf(qreg[dd], k4.x, p);
                p = fmaf(qreg[dd + 1], k4.y, p);
                p = fmaf(qreg[dd + 2], k4.z, p);
                p = fmaf(qreg[dd + 3], k4.w, p);
            }
            sc[j] = p;
        }
        #pragma unroll
        for (int j = 0; j < 32; ++j) {
            float p = sc[j];
            p += __shfl_xor(p, 1);
            p += __shfl_xor(p, 2);
            sc[j] = (t0 + j < SPGc) ? p * 0.125f : -1e30f;
        }
        float mt = sc[0];
        #pragma unroll
        for (int j = 1; j < 32; ++j) mt = fmaxf(mt, sc[j]);
        float mnew = fmaxf(m, mt);
        float f = __expf(m - mnew);
        l *= f;
        #pragma unroll
        for (int dd = 0; dd < 16; ++dd) oacc[dd] *= f;
        #pragma unroll
        for (int j = 0; j < 32; ++j) {
            float p = __expf(sc[j] - mnew);
            l += p;
            #pragma unroll
            for (int dd = 0; dd < 16; dd += 4) {
                const float4 v4 = *(const float4*)&Vs[cb][j][d0 + dd];
                oacc[dd]     = fmaf(p, v4.x, oacc[dd]);
                oacc[dd + 1] = fmaf(p, v4.y, oacc[dd + 1]);
                oacc[dd + 2] = fmaf(p, v4.z, oacc[dd + 2]);
                oacc[dd + 3] = fmaf(p, v4.w, oacc[dd + 3]);
            }
        }
        m = mnew;
        if (it + 1 < NIT) {
            __syncthreads();                    // all waves done reading buffer cb^1 (from it-1)
            int nb = cb ^ 1;
            *(float4*)&Ks[nb][srow][sc8]     = pk0;
            *(float4*)&Ks[nb][srow][sc8 + 4] = pk1;
            *(float4*)&Vs[nb][srow][sc8]     = pv0;
            *(float4*)&Vs[nb][srow][sc8 + 4] = pv1;
            __syncthreads();
        }
    }
    if (rowok) {
        float rinv = 1.0f / l;
        float* op = obuf + (size_t)(g * SPGc + my_s) * 256 + h * 64 + d0;
        #pragma unroll
        for (int dd = 0; dd < 16; ++dd) op[dd] = oacc[dd] * rinv;
    }
}

// ---------------- per-type decoder ----------------
__global__ __launch_bounds__(256) void k_dec(const float* __restrict__ h, const int* __restrict__ types,
        const float* __restrict__ w1, const float* __restrict__ b1,
        const float* __restrict__ w2, const float* __restrict__ b2,
        float* __restrict__ out) {
    int n = blockIdx.x;
    int j = threadIdx.x;
    __shared__ float hrow[256];
    __shared__ float dhid[256];
    hrow[j] = h[(size_t)n * 256 + j];
    __syncthreads();
    int t = types[n];
    const float* W1 = w1 + (size_t)t * 256 * 256;
    float a = b1[t * 256 + j];
    #pragma unroll 8
    for (int k = 0; k < 256; ++k) a = fmaf(hrow[k], W1[k * 256 + j], a);
    dhid[j] = fmaxf(a, 0.f);
    __syncthreads();
    int lane = j & 63, w = j >> 6;
    const float* W2 = w2 + (size_t)t * 256 * 4;
    float p = 0.f;
    #pragma unroll
    for (int q = 0; q < 4; ++q) {
        int kk = lane + 64 * q;
        p = fmaf(dhid[kk], W2[kk * 4 + w], p);
    }
    #pragma unroll
    for (int o2 = 32; o2 > 0; o2 >>= 1) p += __shfl_down(p, o2);
    if (lane == 0) out[(size_t)n * 4 + w] = p + b2[t * 4 + w];
}

extern "C" void kernel_launch(void* const* d_in, const int* in_sizes, int n_in,
                              void* d_out, int out_size, void* d_ws, size_t ws_size,
                              hipStream_t stream) {
    const float* x         = (const float*)d_in[0];
    const float* pe        = (const float*)d_in[1];
    const float* edge_attr = (const float*)d_in[2];
    const int*   eidx      = (const int*)d_in[3];
    const float* enc_w1 = (const float*)d_in[5];
    const float* enc_b1 = (const float*)d_in[6];
    const float* enc_w2 = (const float*)d_in[7];
    const float* enc_b2 = (const float*)d_in[8];
    const float* ee_w1  = (const float*)d_in[9];
    const float* ee_b1  = (const float*)d_in[10];
    const float* ee_w2  = (const float*)d_in[11];
    const float* ee_b2  = (const float*)d_in[12];
    const float* eu_w1  = (const float*)d_in[13];
    const float* eu_b1  = (const float*)d_in[14];
    const float* eu_w2  = (const float*)d_in[15];
    const float* eu_b2  = (const float*)d_in[16];
    const float* nu_w1  = (const float*)d_in[17];
    const float* nu_b1  = (const float*)d_in[18];
    const float* nu_w2  = (const float*)d_in[19];
    const float* nu_b2  = (const float*)d_in[20];
    const float* qkv_w  = (const float*)d_in[21];
    const float* qkv_b  = (const float*)d_in[22];
    const float* out_w  = (const float*)d_in[23];
    const float* out_b  = (const float*)d_in[24];
    const float* fu_w1  = (const float*)d_in[25];
    const float* fu_b1  = (const float*)d_in[26];
    const float* fu_w2  = (const float*)d_in[27];
    const float* fu_b2  = (const float*)d_in[28];
    const float* dec_w1 = (const float*)d_in[29];
    const float* dec_b1 = (const float*)d_in[30];
    const float* dec_w2 = (const float*)d_in[31];
    const float* dec_b2 = (const float*)d_in[32];

    const int* src  = eidx;
    const int* dstp = eidx + NE;

    float* ws = (float*)d_ws;
    float* h_edges = ws;                        // 25.6M f
    float* region  = ws + 25600000;             // 12.8M f: ehid (layer) / qkvf+fin (attn phase)
    float* h_nodes = ws + 38400000;             // 2.56M f
    float* mn_ob   = ws + 40960000;             // 2.56M f (Pa overlay; m_node -> obuf -> hfused)
    float* nhid    = ws + 43520000;             // 2.56M f (Pb overlay)
    int* ibase   = (int*)(ws + 46080000);
    int* types   = ibase;
    int* deg     = ibase + NN;
    int* row_ptr = deg + NN;
    int* cursor  = row_ptr + NN + 1;
    int* csr     = cursor + NN;

    float* ehid = region;                       // [ECHK][256] = 12.8M f (layer phase)
    float* Pa   = mn_ob;                        // dead before k_mnode writes m_node
    float* Pb   = nhid;                         // dead before nu1 writes nhid
    float* qkvf = region;                       // [NN][768] = 7.68M f (attention phase)
    float* fin  = region + 7680000;             // fusion phase

    hipMemsetAsync(deg, 0, NN * sizeof(int), stream);
    k_types<<<(NN + 255) / 256, 256, 0, stream>>>(x, types);
    k_hist<<<(NE + 255) / 256, 256, 0, stream>>>(dstp, deg);
    k_scan<<<1, 256, 0, stream>>>(deg, row_ptr, cursor);
    k_scatter<<<(NE + 255) / 256, 256, 0, stream>>>(dstp, cursor, csr);

    k_enc<<<NN, 256, 0, stream>>>(x, pe, types, enc_w1, enc_b1, enc_w2, enc_b2, h_nodes);

    dim3 gBig((ECHK + 127) / 128, 2);   // (391, 2) = 782 blocks
    dim3 gN((NN + 63) / 64, 2);

    // edge encoder: ehid = relu(edge_attr@ee_w1+b1); h_edges = ehid@ee_w2+b2
    for (int c0 = 0; c0 < NE; c0 += ECHK) {
        gemm64<<<dim3((ECHK + 63) / 64, 4), 256, 0, stream>>>(ECHK, 8, 256,
            edge_attr + (size_t)c0 * 8, 8, ee_w1, ee_b1, ehid);
        gemm_big<false, false, false><<<gBig, 256, 0, stream>>>(ECHK,
            ehid, ee_w2, ee_b2, nullptr, nullptr, 0, nullptr, nullptr,
            nullptr, h_edges + (size_t)c0 * 256);
    }

    // message-passing layers
    for (int l = 0; l < NL; ++l) {
        const float* W1 = eu_w1 + (size_t)l * 768 * 256;
        // Pa = h@W1[0:256], Pb = h@W1[256:512] in one dispatch (grid.z=2)
        gemm_f32<0, false, false, false><<<dim3((NN + 63) / 64, 2, 2), 256, 0, stream>>>(NN, 256, 256,
            h_nodes, nullptr, 256, W1, nullptr, nullptr, 0.f, Pa, 65536, 2560000);
        for (int c0 = 0; c0 < NE; c0 += ECHK) {
            // ehid = relu(h_edges@W1c + Pa[src] + Pb[dst] + b1)
            gemm_big<true, true, false><<<gBig, 256, 0, stream>>>(ECHK,
                h_edges + (size_t)c0 * 256, W1 + 131072, eu_b1 + l * 256,
                src, dstp, c0, Pa, Pb, nullptr, ehid);
            // h_edges += ehid@W2 + b2
            gemm_big<false, false, true><<<gBig, 256, 0, stream>>>(ECHK,
                ehid, eu_w2 + (size_t)l * 65536, eu_b2 + l * 256,
                nullptr, nullptr, 0, nullptr, nullptr,
                h_edges + (size_t)c0 * 256, h_edges + (size_t)c0 * 256);
        }
        k_mnode<<<(NN + 3) / 4, 256, 0, stream>>>(h_edges, row_ptr, csr, mn_ob);
        gemm_f32<2, true, false, true><<<gN, 256, 0, stream>>>(NN, 512, 256,
            h_nodes, mn_ob, 256, nu_w1 + (size_t)l * 131072, nu_b1 + l * 256,
            nullptr, 0.f, nhid, 0, 0);
        gemm_f32<0, false, true, true><<<gN, 256, 0, stream>>>(NN, 256, 256,
            nhid, nullptr, 256, nu_w2 + (size_t)l * 65536, nu_b2 + l * 256,
            h_nodes, 1.f, h_nodes, 0, 0);
    }

    // qkv projection
    gemm_f32<0, false, false, true><<<dim3((NN + 63) / 64, 6), 256, 0, stream>>>(NN, 256, 768,
        h_nodes, nullptr, 256, qkv_w, qkv_b, nullptr, 0.f, qkvf, 0, 0);

    dim3 ga((SPGc + 63) / 64, NG * 4);
    k_attn<<<ga, 256, 0, stream>>>(qkvf, mn_ob);

    // fin = obuf@out_w + out_b + 2*h_nodes ; nhid = relu(fin@fu_w1+b) ; hfused = nhid@fu_w2+b
    gemm_f32<0, false, true, true><<<gN, 256, 0, stream>>>(NN, 256, 256,
        mn_ob, nullptr, 256, out_w, out_b, h_nodes, 2.f, fin, 0, 0);
    gemm_f32<0, true, false, true><<<gN, 256, 0, stream>>>(NN, 256, 256,
        fin, nullptr, 256, fu_w1, fu_b1, nullptr, 0.f, nhid, 0, 0);
    gemm_f32<0, false, false, true><<<gN, 256, 0, stream>>>(NN, 256, 256,
        nhid, nullptr, 256, fu_w2, fu_b2, nullptr, 0.f, mn_ob, 0, 0);

    k_dec<<<NN, 256, 0, stream>>>(mn_ob, types, dec_w1, dec_b1, dec_w2, dec_b2, (float*)d_out);
}

// Round 15
// 3771.984 us; speedup vs baseline: 1.4085x; 1.4085x over previous
//
#include <hip/hip_runtime.h>
#include <hip/hip_bf16.h>
#include <math.h>

#define NN 10000
#define NE 100000
#define SPGc 1250
#define NG 8
#define NL 5
#define ECHK 50000

__device__ __forceinline__ int imin(int a, int b) { return a < b ? a : b; }

// ---------------- node types ----------------
__global__ __launch_bounds__(256) void k_types(const float* __restrict__ x, int* __restrict__ types) {
    int i = blockIdx.x * 256 + threadIdx.x;
    if (i < NN) {
        float v = rintf(x[(size_t)i * 16 + 2] * 3.0f);
        v = fminf(fmaxf(v, 1.0f), 3.0f);
        types[i] = (int)v - 1;
    }
}

// ---------------- CSR build ----------------
__global__ __launch_bounds__(256) void k_hist(const int* __restrict__ dst, int* __restrict__ deg) {
    int e = blockIdx.x * 256 + threadIdx.x;
    if (e < NE) atomicAdd(&deg[dst[e]], 1);
}

__global__ __launch_bounds__(256) void k_scan(const int* __restrict__ deg, int* __restrict__ row_ptr,
                                              int* __restrict__ cursor) {
    __shared__ int buf[256];
    int tid = threadIdx.x;
    int base = 0;
    for (int c = 0; c < NN; c += 256) {
        int i = c + tid;
        int v = (i < NN) ? deg[i] : 0;
        buf[tid] = v;
        __syncthreads();
        for (int off = 1; off < 256; off <<= 1) {
            int t = (tid >= off) ? buf[tid - off] : 0;
            __syncthreads();
            buf[tid] += t;
            __syncthreads();
        }
        if (i < NN) {
            row_ptr[i + 1] = base + buf[tid];
            cursor[i] = base + buf[tid] - v;
        }
        __syncthreads();
        base += buf[255];
        __syncthreads();
    }
    if (tid == 0) row_ptr[0] = 0;
}

__global__ __launch_bounds__(256) void k_scatter(const int* __restrict__ dst, int* __restrict__ cursor,
                                                 int* __restrict__ csr) {
    int e = blockIdx.x * 256 + threadIdx.x;
    if (e < NE) {
        int p = atomicAdd(&cursor[dst[e]], 1);
        csr[p] = e;
    }
}

// ---------------- per-type node encoder (fp32) ----------------
__global__ __launch_bounds__(256) void k_enc(const float* __restrict__ x, const float* __restrict__ pe,
        const int* __restrict__ types,
        const float* __restrict__ w1, const float* __restrict__ b1,
        const float* __restrict__ w2, const float* __restrict__ b2,
        float* __restrict__ h_nodes) {
    int n = blockIdx.x;
    int j = threadIdx.x;
    __shared__ float inp[21];
    __shared__ float hid[256];
    if (j < 16) inp[j] = x[(size_t)n * 16 + j];
    else if (j < 21) inp[j] = pe[(size_t)n * 5 + (j - 16)];
    __syncthreads();
    int t = types[n];
    const float* W1 = w1 + (size_t)t * 21 * 256;
    float a = b1[t * 256 + j];
    #pragma unroll
    for (int i = 0; i < 21; ++i) a = fmaf(inp[i], W1[i * 256 + j], a);
    hid[j] = fmaxf(a, 0.f);
    __syncthreads();
    const float* W2 = w2 + (size_t)t * 256 * 256;
    float o = b2[t * 256 + j];
    #pragma unroll 8
    for (int k = 0; k < 256; ++k) o = fmaf(hid[k], W2[k * 256 + j], o);
    h_nodes[(size_t)n * 256 + j] = o;
}

// ---------------- small fp32 GEMM (edge encoder layer 1, K=8), relu out ----------------
__global__ __launch_bounds__(256) void gemm64(int Mrows, int K, int Nout,
        const float* __restrict__ A0, int lda,
        const float* __restrict__ W, const float* __restrict__ bias,
        float* __restrict__ C) {
    __shared__ __align__(16) float As[16][68];
    __shared__ __align__(16) float Ws[16][64];
    int tid = threadIdx.x;
    int tx = tid & 15, ty = tid >> 4;
    int blockRow = blockIdx.x * 64;
    int ncol0 = blockIdx.y * 64;
    float acc[4][4];
    #pragma unroll
    for (int i = 0; i < 4; ++i)
        #pragma unroll
        for (int j = 0; j < 4; ++j) acc[i][j] = 0.f;

    for (int k0 = 0; k0 < K; k0 += 16) {
        #pragma unroll
        for (int i = 0; i < 4; ++i) {
            int id = tid + 256 * i;
            int kk = id & 15, r = id >> 4;
            int grow = blockRow + r;
            int k = k0 + kk;
            float v = 0.f;
            if (grow < Mrows && k < K) v = A0[(size_t)grow * lda + k];
            As[kk][r] = v;
        }
        #pragma unroll
        for (int i = 0; i < 4; ++i) {
            int id = tid + 256 * i;
            int c = id & 63, kk = id >> 6;
            int k = k0 + kk;
            Ws[kk][c] = (k < K) ? W[(size_t)k * Nout + ncol0 + c] : 0.f;
        }
        __syncthreads();
        #pragma unroll
        for (int kk = 0; kk < 16; ++kk) {
            const float4 a4 = *(const float4*)&As[kk][ty << 2];
            const float4 w4 = *(const float4*)&Ws[kk][tx << 2];
            float av[4] = {a4.x, a4.y, a4.z, a4.w};
            float wv[4] = {w4.x, w4.y, w4.z, w4.w};
            #pragma unroll
            for (int i = 0; i < 4; ++i)
                #pragma unroll
                for (int j = 0; j < 4; ++j)
                    acc[i][j] = fmaf(av[i], wv[j], acc[i][j]);
        }
        __syncthreads();
    }
    #pragma unroll
    for (int i = 0; i < 4; ++i) {
        int grow = blockRow + (ty << 2) + i;
        if (grow >= Mrows) continue;
        size_t base = (size_t)grow * Nout + ncol0 + (tx << 2);
        #pragma unroll
        for (int j = 0; j < 4; ++j)
            C[base + j] = fmaxf(acc[i][j] + bias[ncol0 + (tx << 2) + j], 0.f);
    }
}

// ---------------- big edge GEMM: 128x128 tile (Nout=256, y half), K=256, 8x8/thread ----------------
// Software-pipelined staging: prefetch next k-tile into regs during compute.
template<bool GATHER, bool RELU, bool RES>
__global__ __launch_bounds__(256) void gemm_big(int Mrows,
        const float* __restrict__ A,
        const float* __restrict__ W, const float* __restrict__ bias,
        const int* __restrict__ gs, const int* __restrict__ gd, int gOfs,
        const float* __restrict__ Pa, const float* __restrict__ Pb,
        const float* __restrict__ Res, float* __restrict__ C) {
    __shared__ __align__(16) float As[16][132];      // 8448 B, [k][row]
    __shared__ __align__(16) float Ws[16][16][10];   // 6400 B, [k][colgroup][8 used]
    int tid = threadIdx.x;
    int blockRow = blockIdx.x * 128;
    int ncol0 = blockIdx.y * 128;
    int rg = tid >> 4, cg = tid & 15;                // rows rg*8..+7, cols cg*8..+7
    int srow = tid >> 1, skh = (tid & 1) * 8;        // A staging
    int swk = tid >> 4, scg = tid & 15;              // W staging
    float acc[8][8];
    #pragma unroll
    for (int i = 0; i < 8; ++i)
        #pragma unroll
        for (int n = 0; n < 8; ++n) acc[i][n] = 0.f;

    int arow = imin(blockRow + srow, Mrows - 1);
    const float* aP = A + (size_t)arow * 256 + skh;
    const float* wP = W + (size_t)swk * 256 + ncol0 + scg * 8;

    float4 pa0 = *(const float4*)(aP);
    float4 pa1 = *(const float4*)(aP + 4);
    float4 pw0 = *(const float4*)(wP);
    float4 pw1 = *(const float4*)(wP + 4);

    for (int k0 = 0; k0 < 256; k0 += 16) {
        As[skh + 0][srow] = pa0.x; As[skh + 1][srow] = pa0.y;
        As[skh + 2][srow] = pa0.z; As[skh + 3][srow] = pa0.w;
        As[skh + 4][srow] = pa1.x; As[skh + 5][srow] = pa1.y;
        As[skh + 6][srow] = pa1.z; As[skh + 7][srow] = pa1.w;
        *(float4*)&Ws[swk][scg][0] = pw0;
        *(float4*)&Ws[swk][scg][4] = pw1;
        __syncthreads();
        if (k0 + 16 < 256) {
            pa0 = *(const float4*)(aP + k0 + 16);
            pa1 = *(const float4*)(aP + k0 + 20);
            const float* wn = wP + (size_t)(k0 + 16) * 256;
            pw0 = *(const float4*)(wn);
            pw1 = *(const float4*)(wn + 4);
        }
        #pragma unroll
        for (int kk = 0; kk < 16; ++kk) {
            const float4 a0 = *(const float4*)&As[kk][rg << 3];
            const float4 a1 = *(const float4*)&As[kk][(rg << 3) + 4];
            float av[8] = {a0.x, a0.y, a0.z, a0.w, a1.x, a1.y, a1.z, a1.w};
            const float4 w0 = *(const float4*)&Ws[kk][cg][0];
            const float4 w1 = *(const float4*)&Ws[kk][cg][4];
            float wv[8] = {w0.x, w0.y, w0.z, w0.w, w1.x, w1.y, w1.z, w1.w};
            #pragma unroll
            for (int i = 0; i < 8; ++i)
                #pragma unroll
                for (int j = 0; j < 8; ++j)
                    acc[i][j] = fmaf(av[i], wv[j], acc[i][j]);
        }
        __syncthreads();
    }
    // ---- epilogue ----
    int colb = ncol0 + (cg << 3);
    #pragma unroll
    for (int i = 0; i < 8; ++i) {
        int row = blockRow + (rg << 3) + i;
        if (row >= Mrows) continue;
        size_t base = (size_t)row * 256 + colb;
        const float* par = nullptr;
        const float* pbr = nullptr;
        if (GATHER) {
            par = Pa + (size_t)gs[gOfs + row] * 256 + colb;
            pbr = Pb + (size_t)gd[gOfs + row] * 256 + colb;
        }
        #pragma unroll
        for (int q = 0; q < 2; ++q) {
            const float4 b4 = *(const float4*)(bias + colb + q * 4);
            float v[4] = {acc[i][q * 4 + 0] + b4.x, acc[i][q * 4 + 1] + b4.y,
                          acc[i][q * 4 + 2] + b4.z, acc[i][q * 4 + 3] + b4.w};
            if (GATHER) {
                const float4 pa4 = *(const float4*)(par + q * 4);
                const float4 pb4 = *(const float4*)(pbr + q * 4);
                v[0] += pa4.x + pb4.x; v[1] += pa4.y + pb4.y;
                v[2] += pa4.z + pb4.z; v[3] += pa4.w + pb4.w;
            }
            if (RELU) {
                v[0] = fmaxf(v[0], 0.f); v[1] = fmaxf(v[1], 0.f);
                v[2] = fmaxf(v[2], 0.f); v[3] = fmaxf(v[3], 0.f);
            }
            if (RES) {
                const float4 rv = *(const float4*)(Res + base + q * 4);
                v[0] += rv.x; v[1] += rv.y; v[2] += rv.z; v[3] += rv.w;
            }
            float4 o; o.x = v[0]; o.y = v[1]; o.z = v[2]; o.w = v[3];
            *(float4*)(C + base + q * 4) = o;
        }
    }
}

// ---------------- node fp32 GEMM: BM=64, BN=128, BK=16, 4x8/thread; pipelined; grid.z batches W/C ----------------
template<int AMODE, bool RELU, bool HASRES, bool HASBIAS>
__global__ __launch_bounds__(256) void gemm_f32(int Mrows, int K, int Nout,
        const float* __restrict__ A0, const float* __restrict__ A1, int lda,
        const float* __restrict__ W, const float* __restrict__ bias,
        const float* __restrict__ ResF, float resScale,
        float* __restrict__ C, int zW, int zC) {
    __shared__ __align__(16) float As[16][68];
    __shared__ __align__(16) float Ws[16][16][10];
    int tid = threadIdx.x;
    int blockRow = blockIdx.x * 64;
    int ncol0 = blockIdx.y * 128;
    W += (size_t)blockIdx.z * zW;
    C += (size_t)blockIdx.z * zC;
    int rg = tid >> 4, cg = tid & 15;
    int sar = tid >> 2, sak = (tid & 3) * 4;
    int swk = tid >> 4, scg = tid & 15;
    float acc[4][8];
    #pragma unroll
    for (int i = 0; i < 4; ++i)
        #pragma unroll
        for (int n = 0; n < 8; ++n) acc[i][n] = 0.f;

    int arowA = imin(blockRow + sar, Mrows - 1);
    const float* wPb = W + (size_t)swk * Nout + ncol0 + scg * 8;

    float4 pa, pw0, pw1;
    {
        if (AMODE == 0) {
            pa = *(const float4*)(A0 + (size_t)arowA * lda + sak);
        } else {
            int k = sak;
            pa = (k < 256) ? *(const float4*)(A0 + (size_t)arowA * 256 + k)
                           : *(const float4*)(A1 + (size_t)arowA * 256 + (k - 256));
        }
        pw0 = *(const float4*)(wPb);
        pw1 = *(const float4*)(wPb + 4);
    }

    for (int k0 = 0; k0 < K; k0 += 16) {
        As[sak + 0][sar] = pa.x;
        As[sak + 1][sar] = pa.y;
        As[sak + 2][sar] = pa.z;
        As[sak + 3][sar] = pa.w;
        *(float4*)&Ws[swk][scg][0] = pw0;
        *(float4*)&Ws[swk][scg][4] = pw1;
        __syncthreads();
        if (k0 + 16 < K) {
            int kn = k0 + 16 + sak;
            if (AMODE == 0) {
                pa = *(const float4*)(A0 + (size_t)arowA * lda + kn);
            } else {
                pa = (kn < 256) ? *(const float4*)(A0 + (size_t)arowA * 256 + kn)
                                : *(const float4*)(A1 + (size_t)arowA * 256 + (kn - 256));
            }
            const float* wn = wPb + (size_t)(k0 + 16) * Nout;
            pw0 = *(const float4*)(wn);
            pw1 = *(const float4*)(wn + 4);
        }
        #pragma unroll
        for (int kk = 0; kk < 16; ++kk) {
            const float4 a4 = *(const float4*)&As[kk][rg << 2];
            float av[4] = {a4.x, a4.y, a4.z, a4.w};
            const float4 w0 = *(const float4*)&Ws[kk][cg][0];
            const float4 w1 = *(const float4*)&Ws[kk][cg][4];
            float wv[8] = {w0.x, w0.y, w0.z, w0.w, w1.x, w1.y, w1.z, w1.w};
            #pragma unroll
            for (int i = 0; i < 4; ++i)
                #pragma unroll
                for (int j = 0; j < 8; ++j)
                    acc[i][j] = fmaf(av[i], wv[j], acc[i][j]);
        }
        __syncthreads();
    }
    #pragma unroll
    for (int i = 0; i < 4; ++i) {
        int grow = blockRow + (rg << 2) + i;
        if (grow >= Mrows) continue;
        size_t crow = (size_t)grow;
        int colb = ncol0 + (cg << 3);
        #pragma unroll
        for (int q = 0; q < 2; ++q) {
            float v[4];
            #pragma unroll
            for (int j = 0; j < 4; ++j) v[j] = acc[i][q * 4 + j];
            if (HASBIAS) {
                const float4 b4 = *(const float4*)(bias + colb + q * 4);
                v[0] += b4.x; v[1] += b4.y; v[2] += b4.z; v[3] += b4.w;
            }
            if (RELU) {
                v[0] = fmaxf(v[0], 0.f); v[1] = fmaxf(v[1], 0.f);
                v[2] = fmaxf(v[2], 0.f); v[3] = fmaxf(v[3], 0.f);
            }
            if (HASRES) {
                const float4 rv = *(const float4*)(ResF + crow * Nout + colb + q * 4);
                v[0] += resScale * rv.x; v[1] += resScale * rv.y;
                v[2] += resScale * rv.z; v[3] += resScale * rv.w;
            }
            float4 o; o.x = v[0]; o.y = v[1]; o.z = v[2]; o.w = v[3];
            *(float4*)(C + crow * Nout + colb + q * 4) = o;
        }
    }
}

// ---------------- segment-sum ----------------
__global__ __launch_bounds__(256) void k_mnode(const float* __restrict__ h_edges,
        const int* __restrict__ row_ptr, const int* __restrict__ csr, float* __restrict__ m_node) {
    int n = blockIdx.x * 4 + (threadIdx.x >> 6);
    int lane = threadIdx.x & 63;
    if (n >= NN) return;
    float a0 = 0.f, a1 = 0.f, a2 = 0.f, a3 = 0.f;
    int s = row_ptr[n], e = row_ptr[n + 1];
    for (int i = s; i < e; ++i) {
        int ed = csr[i];
        const float4 v = *(const float4*)(h_edges + (size_t)ed * 256 + (lane << 2));
        a0 += v.x; a1 += v.y; a2 += v.z; a3 += v.w;
    }
    float4 r; r.x = a0; r.y = a1; r.z = a2; r.w = a3;
    *(float4*)(m_node + (size_t)n * 256 + (lane << 2)) = r;
}

// ---------------- flash attention (round-12 version: fp32, float4 staging, padded LDS) ----------------
__global__ __launch_bounds__(256) void k_attn(const float* __restrict__ qkv, float* __restrict__ obuf) {
    int gh = blockIdx.y;
    int g = gh >> 2, h = gh & 3;
    int q0 = blockIdx.x * 64;
    int tid = threadIdx.x;
    int r = tid >> 2, q4 = tid & 3;
    int d0 = q4 * 16;
    __shared__ __align__(16) float Ks[32][68];
    __shared__ __align__(16) float Vs[32][68];
    const float* base = qkv + (size_t)g * SPGc * 768;
    int my_s = q0 + r;
    bool rowok = my_s < SPGc;
    float qreg[16];
    #pragma unroll
    for (int dd = 0; dd < 16; ++dd) qreg[dd] = 0.f;
    if (rowok) {
        const float* qp = base + (size_t)my_s * 768 + h * 64 + d0;
        #pragma unroll
        for (int dd = 0; dd < 16; ++dd) qreg[dd] = qp[dd];
    }
    float m = -1e30f, l = 0.f;
    float oacc[16];
    #pragma unroll
    for (int dd = 0; dd < 16; ++dd) oacc[dd] = 0.f;

    int srow = tid >> 3, sc8 = (tid & 7) * 8;
    for (int t0 = 0; t0 < SPGc; t0 += 32) {
        {
            int s = t0 + srow;
            float4 k0v = {0,0,0,0}, k1v = {0,0,0,0}, v0v = {0,0,0,0}, v1v = {0,0,0,0};
            if (s < SPGc) {
                const float* kp = base + (size_t)s * 768 + h * 64 + sc8;
                k0v = *(const float4*)(kp + 256);
                k1v = *(const float4*)(kp + 260);
                v0v = *(const float4*)(kp + 512);
                v1v = *(const float4*)(kp + 516);
            }
            *(float4*)&Ks[srow][sc8]     = k0v;
            *(float4*)&Ks[srow][sc8 + 4] = k1v;
            *(float4*)&Vs[srow][sc8]     = v0v;
            *(float4*)&Vs[srow][sc8 + 4] = v1v;
        }
        __syncthreads();
        float sc[32];
        #pragma unroll
        for (int j = 0; j < 32; ++j) {
            float p = 0.f;
            #pragma unroll
            for (int dd = 0; dd < 16; dd += 4) {
                const float4 k4 = *(const float4*)&Ks[j][d0 + dd];
                p = fmaf(qreg[dd], k4.x, p);
                p = fmaf(qreg[dd + 1], k4.y, p);
                p = fmaf(qreg[dd + 2], k4.z, p);
                p = fmaf(qreg[dd + 3], k4.w, p);
            }
            sc[j] = p;
        }
        #pragma unroll
        for (int j = 0; j < 32; ++j) {
            float p = sc[j];
            p += __shfl_xor(p, 1);
            p += __shfl_xor(p, 2);
            sc[j] = (t0 + j < SPGc) ? p * 0.125f : -1e30f;
        }
        float mt = sc[0];
        #pragma unroll
        for (int j = 1; j < 32; ++j) mt = fmaxf(mt, sc[j]);
        float mnew = fmaxf(m, mt);
        float f = __expf(m - mnew);
        l *= f;
        #pragma unroll
        for (int dd = 0; dd < 16; ++dd) oacc[dd] *= f;
        #pragma unroll
        for (int j = 0; j < 32; ++j) {
            float p = __expf(sc[j] - mnew);
            l += p;
            #pragma unroll
            for (int dd = 0; dd < 16; dd += 4) {
                const float4 v4 = *(const float4*)&Vs[j][d0 + dd];
                oacc[dd]     = fmaf(p, v4.x, oacc[dd]);
                oacc[dd + 1] = fmaf(p, v4.y, oacc[dd + 1]);
                oacc[dd + 2] = fmaf(p, v4.z, oacc[dd + 2]);
                oacc[dd + 3] = fmaf(p, v4.w, oacc[dd + 3]);
            }
        }
        m = mnew;
        __syncthreads();
    }
    if (rowok) {
        float rinv = 1.0f / l;
        float* op = obuf + (size_t)(g * SPGc + my_s) * 256 + h * 64 + d0;
        #pragma unroll
        for (int dd = 0; dd < 16; ++dd) op[dd] = oacc[dd] * rinv;
    }
}

// ---------------- per-type decoder ----------------
__global__ __launch_bounds__(256) void k_dec(const float* __restrict__ h, const int* __restrict__ types,
        const float* __restrict__ w1, const float* __restrict__ b1,
        const float* __restrict__ w2, const float* __restrict__ b2,
        float* __restrict__ out) {
    int n = blockIdx.x;
    int j = threadIdx.x;
    __shared__ float hrow[256];
    __shared__ float dhid[256];
    hrow[j] = h[(size_t)n * 256 + j];
    __syncthreads();
    int t = types[n];
    const float* W1 = w1 + (size_t)t * 256 * 256;
    float a = b1[t * 256 + j];
    #pragma unroll 8
    for (int k = 0; k < 256; ++k) a = fmaf(hrow[k], W1[k * 256 + j], a);
    dhid[j] = fmaxf(a, 0.f);
    __syncthreads();
    int lane = j & 63, w = j >> 6;
    const float* W2 = w2 + (size_t)t * 256 * 4;
    float p = 0.f;
    #pragma unroll
    for (int q = 0; q < 4; ++q) {
        int kk = lane + 64 * q;
        p = fmaf(dhid[kk], W2[kk * 4 + w], p);
    }
    #pragma unroll
    for (int o2 = 32; o2 > 0; o2 >>= 1) p += __shfl_down(p, o2);
    if (lane == 0) out[(size_t)n * 4 + w] = p + b2[t * 4 + w];
}

extern "C" void kernel_launch(void* const* d_in, const int* in_sizes, int n_in,
                              void* d_out, int out_size, void* d_ws, size_t ws_size,
                              hipStream_t stream) {
    const float* x         = (const float*)d_in[0];
    const float* pe        = (const float*)d_in[1];
    const float* edge_attr = (const float*)d_in[2];
    const int*   eidx      = (const int*)d_in[3];
    const float* enc_w1 = (const float*)d_in[5];
    const float* enc_b1 = (const float*)d_in[6];
    const float* enc_w2 = (const float*)d_in[7];
    const float* enc_b2 = (const float*)d_in[8];
    const float* ee_w1  = (const float*)d_in[9];
    const float* ee_b1  = (const float*)d_in[10];
    const float* ee_w2  = (const float*)d_in[11];
    const float* ee_b2  = (const float*)d_in[12];
    const float* eu_w1  = (const float*)d_in[13];
    const float* eu_b1  = (const float*)d_in[14];
    const float* eu_w2  = (const float*)d_in[15];
    const float* eu_b2  = (const float*)d_in[16];
    const float* nu_w1  = (const float*)d_in[17];
    const float* nu_b1  = (const float*)d_in[18];
    const float* nu_w2  = (const float*)d_in[19];
    const float* nu_b2  = (const float*)d_in[20];
    const float* qkv_w  = (const float*)d_in[21];
    const float* qkv_b  = (const float*)d_in[22];
    const float* out_w  = (const float*)d_in[23];
    const float* out_b  = (const float*)d_in[24];
    const float* fu_w1  = (const float*)d_in[25];
    const float* fu_b1  = (const float*)d_in[26];
    const float* fu_w2  = (const float*)d_in[27];
    const float* fu_b2  = (const float*)d_in[28];
    const float* dec_w1 = (const float*)d_in[29];
    const float* dec_b1 = (const float*)d_in[30];
    const float* dec_w2 = (const float*)d_in[31];
    const float* dec_b2 = (const float*)d_in[32];

    const int* src  = eidx;
    const int* dstp = eidx + NE;

    float* ws = (float*)d_ws;
    float* h_edges = ws;                        // 25.6M f
    float* region  = ws + 25600000;             // 12.8M f: ehid (layer) / qkvf+fin (attn phase)
    float* h_nodes = ws + 38400000;             // 2.56M f
    float* mn_ob   = ws + 40960000;             // 2.56M f (Pa overlay; m_node -> obuf -> hfused)
    float* nhid    = ws + 43520000;             // 2.56M f (Pb overlay)
    int* ibase   = (int*)(ws + 46080000);
    int* types   = ibase;
    int* deg     = ibase + NN;
    int* row_ptr = deg + NN;
    int* cursor  = row_ptr + NN + 1;
    int* csr     = cursor + NN;

    float* ehid = region;                       // [ECHK][256] = 12.8M f (layer phase)
    float* Pa   = mn_ob;                        // dead before k_mnode writes m_node
    float* Pb   = nhid;                         // dead before nu1 writes nhid
    float* qkvf = region;                       // [NN][768] = 7.68M f (attention phase)
    float* fin  = region + 7680000;             // fusion phase

    hipMemsetAsync(deg, 0, NN * sizeof(int), stream);
    k_types<<<(NN + 255) / 256, 256, 0, stream>>>(x, types);
    k_hist<<<(NE + 255) / 256, 256, 0, stream>>>(dstp, deg);
    k_scan<<<1, 256, 0, stream>>>(deg, row_ptr, cursor);
    k_scatter<<<(NE + 255) / 256, 256, 0, stream>>>(dstp, cursor, csr);

    k_enc<<<NN, 256, 0, stream>>>(x, pe, types, enc_w1, enc_b1, enc_w2, enc_b2, h_nodes);

    dim3 gBig((ECHK + 127) / 128, 2);   // (391, 2) = 782 blocks
    dim3 gN((NN + 63) / 64, 2);

    // edge encoder: ehid = relu(edge_attr@ee_w1+b1); h_edges = ehid@ee_w2+b2
    for (int c0 = 0; c0 < NE; c0 += ECHK) {
        gemm64<<<dim3((ECHK + 63) / 64, 4), 256, 0, stream>>>(ECHK, 8, 256,
            edge_attr + (size_t)c0 * 8, 8, ee_w1, ee_b1, ehid);
        gemm_big<false, false, false><<<gBig, 256, 0, stream>>>(ECHK,
            ehid, ee_w2, ee_b2, nullptr, nullptr, 0, nullptr, nullptr,
            nullptr, h_edges + (size_t)c0 * 256);
    }

    // message-passing layers
    for (int l = 0; l < NL; ++l) {
        const float* W1 = eu_w1 + (size_t)l * 768 * 256;
        // Pa = h@W1[0:256], Pb = h@W1[256:512] in one dispatch (grid.z=2)
        gemm_f32<0, false, false, false><<<dim3((NN + 63) / 64, 2, 2), 256, 0, stream>>>(NN, 256, 256,
            h_nodes, nullptr, 256, W1, nullptr, nullptr, 0.f, Pa, 65536, 2560000);
        for (int c0 = 0; c0 < NE; c0 += ECHK) {
            // ehid = relu(h_edges@W1c + Pa[src] + Pb[dst] + b1)
            gemm_big<true, true, false><<<gBig, 256, 0, stream>>>(ECHK,
                h_edges + (size_t)c0 * 256, W1 + 131072, eu_b1 + l * 256,
                src, dstp, c0, Pa, Pb, nullptr, ehid);
            // h_edges += ehid@W2 + b2
            gemm_big<false, false, true><<<gBig, 256, 0, stream>>>(ECHK,
                ehid, eu_w2 + (size_t)l * 65536, eu_b2 + l * 256,
                nullptr, nullptr, 0, nullptr, nullptr,
                h_edges + (size_t)c0 * 256, h_edges + (size_t)c0 * 256);
        }
        k_mnode<<<(NN + 3) / 4, 256, 0, stream>>>(h_edges, row_ptr, csr, mn_ob);
        gemm_f32<2, true, false, true><<<gN, 256, 0, stream>>>(NN, 512, 256,
            h_nodes, mn_ob, 256, nu_w1 + (size_t)l * 131072, nu_b1 + l * 256,
            nullptr, 0.f, nhid, 0, 0);
        gemm_f32<0, false, true, true><<<gN, 256, 0, stream>>>(NN, 256, 256,
            nhid, nullptr, 256, nu_w2 + (size_t)l * 65536, nu_b2 + l * 256,
            h_nodes, 1.f, h_nodes, 0, 0);
    }

    // qkv projection
    gemm_f32<0, false, false, true><<<dim3((NN + 63) / 64, 6), 256, 0, stream>>>(NN, 256, 768,
        h_nodes, nullptr, 256, qkv_w, qkv_b, nullptr, 0.f, qkvf, 0, 0);

    dim3 ga((SPGc + 63) / 64, NG * 4);
    k_attn<<<ga, 256, 0, stream>>>(qkvf, mn_ob);

    // fin = obuf@out_w + out_b + 2*h_nodes ; nhid = relu(fin@fu_w1+b) ; hfused = nhid@fu_w2+b
    gemm_f32<0, false, true, true><<<gN, 256, 0, stream>>>(NN, 256, 256,
        mn_ob, nullptr, 256, out_w, out_b, h_nodes, 2.f, fin, 0, 0);
    gemm_f32<0, true, false, true><<<gN, 256, 0, stream>>>(NN, 256, 256,
        fin, nullptr, 256, fu_w1, fu_b1, nullptr, 0.f, nhid, 0, 0);
    gemm_f32<0, false, false, true><<<gN, 256, 0, stream>>>(NN, 256, 256,
        nhid, nullptr, 256, fu_w2, fu_b2, nullptr, 0.f, mn_ob, 0, 0);

    k_dec<<<NN, 256, 0, stream>>>(mn_ob, types, dec_w1, dec_b1, dec_w2, dec_b2, (float*)d_out);
}